// Round 1
// baseline (279.060 us; speedup 1.0000x reference)
//
#include <hip/hip_runtime.h>
#include <stdint.h>

#define C_DIM 256
#define L_DIM 8192
#define B_DIM 8
#define SKIP_OFF ((size_t)B_DIM * C_DIM * L_DIM)

using short8  = __attribute__((ext_vector_type(8))) short;
using floatx4 = __attribute__((ext_vector_type(4))) float;
typedef unsigned short ushort_t;

__device__ __forceinline__ ushort_t f2bf(float f) {
    union { float f; uint32_t u; } v; v.f = f;
    uint32_t u = v.u;
    return (ushort_t)((u + 0x7fff + ((u >> 16) & 1)) >> 16);
}
__device__ __forceinline__ float bf2f(ushort_t h) {
    union { uint32_t u; float f; } v; v.u = ((uint32_t)h) << 16;
    return v.f;
}

// frag-linear 32x256 bf16 tile: element (l, c) at
// [l>>4][c>>5][l&15][(c>>3)&3][c&7]  -> B-frag reads are lane-linear ds_read_b128
__device__ __forceinline__ int fragaddr(int l, int c) {
    return ((((l >> 4) * 8 + (c >> 5)) * 16 + (l & 15)) * 4 + ((c >> 3) & 3)) * 8 + (c & 7);
}

// ---------------------------------------------------------------------------
// K0: weight prep: wb bf16[512][256] = [w_main;w_skip]; wrb bf16[64][256];
// wsb bf16[128][64] (= w_span zero-padded from 112 to 128 rows)
// ---------------------------------------------------------------------------
__global__ __launch_bounds__(256) void k0_prep(const float* __restrict__ wm,
                                               const float* __restrict__ wk,
                                               const float* __restrict__ wr,
                                               const float* __restrict__ wsp,
                                               ushort_t* __restrict__ wb,
                                               ushort_t* __restrict__ wrb,
                                               ushort_t* __restrict__ wsb) {
    int i = blockIdx.x * 256 + threadIdx.x;
    if (i < 65536) wb[i] = f2bf(wm[i]);
    else if (i < 131072) wb[i] = f2bf(wk[i - 65536]);
    else if (i < 147456) wrb[i - 131072] = f2bf(wr[i - 131072]);
    else if (i < 155648) {
        int j = i - 147456;
        int r = j >> 6, cc = j & 63;
        wsb[j] = (r < 112) ? f2bf(wsp[r * 64 + cc]) : (ushort_t)0;
    }
}

// ---------------------------------------------------------------------------
// K_FUSED: per (b, 32-l tile): x -> frag LDS; h = relu(Wr@x) MFMA;
// ker = Wsp@h MFMA -> LDS; involution from LDS windows (+reg halo);
// PReLU -> LayerNorm (in-place over x tile) -> 512x256 MFMA GEMM -> out.
// No xbT/kb intermediates, no second latency-bound kernel.
// ---------------------------------------------------------------------------
#define KS_STR 40
__global__ __launch_bounds__(256) void k_fused(const float* __restrict__ x,
                                               const ushort_t* __restrict__ wrb,
                                               const ushort_t* __restrict__ wsb,
                                               const ushort_t* __restrict__ wb,
                                               const float* __restrict__ pa,
                                               const float* __restrict__ gamma,
                                               const float* __restrict__ beta,
                                               float* __restrict__ out) {
    __shared__ __align__(16) ushort_t xsF[8192];        // 16384 B frag x tile; later xn
    __shared__ __align__(16) ushort_t hTF[2048];        // 4096 B h frag; later LN reductions
    __shared__ __align__(16) ushort_t ks[112 * KS_STR]; // 8960 B ker tile

    int t = threadIdx.x;
    int b = blockIdx.x >> 8;
    int l0 = (blockIdx.x & 255) * 32;
    const float* xb = x + (size_t)b * C_DIM * L_DIM;

    // halo: 3 left + 3 right per channel, fp32 registers (issued first, long-latency)
    int c = t;
    float haloL[3], haloR[3];
#pragma unroll
    for (int j = 0; j < 3; ++j) {
        int ll = l0 - 3 + j;
        haloL[j] = (ll >= 0) ? xb[(size_t)c * L_DIM + ll] : 0.f;
        int rr = l0 + 32 + j;
        haloR[j] = (rr < L_DIM) ? xb[(size_t)c * L_DIM + rr] : 0.f;
    }

    // P1: load x tile (coalesced float4 along l), cvt, scatter to frag LDS
    {
        int lo = (t & 7) * 4;
        int cb = t >> 3;
#pragma unroll
        for (int j = 0; j < 8; ++j) {
            int cc = cb + j * 32;
            float4 v = *(const float4*)&xb[(size_t)cc * L_DIM + l0 + lo];
            xsF[fragaddr(lo + 0, cc)] = f2bf(v.x);
            xsF[fragaddr(lo + 1, cc)] = f2bf(v.y);
            xsF[fragaddr(lo + 2, cc)] = f2bf(v.z);
            xsF[fragaddr(lo + 3, cc)] = f2bf(v.w);
        }
    }
    __syncthreads();

    int w = t >> 6, lane = t & 63, lr = lane & 15, quad = lane >> 4;

    // P2: h-GEMM M=64,K=256,N=32. Wave w -> rows w*16..+15. ReLU -> hTF frag.
    {
        short8 af[8];
#pragma unroll
        for (int s = 0; s < 8; ++s)
            af[s] = *(const short8*)&wrb[(w * 16 + lr) * 256 + s * 32 + quad * 8];
#pragma unroll
        for (int nt = 0; nt < 2; ++nt) {
            floatx4 a4 = {0.f, 0.f, 0.f, 0.f};
#pragma unroll
            for (int s = 0; s < 8; ++s) {
                short8 bf = *(const short8*)&xsF[(((nt * 8 + s) * 16 + lr) * 4 + quad) * 8];
                a4 = __builtin_amdgcn_mfma_f32_16x16x32_bf16(af[s], bf, a4, 0, 0, 0);
            }
            // C/D: n = nt*16+lr, r = w*16 + quad*4 + reg
            int r0 = w * 16 + quad * 4;
            int sK = r0 >> 5, qK = (r0 >> 3) & 3, j0 = r0 & 7;
            ushort4 hv;
            hv.x = f2bf(fmaxf(a4[0], 0.f));
            hv.y = f2bf(fmaxf(a4[1], 0.f));
            hv.z = f2bf(fmaxf(a4[2], 0.f));
            hv.w = f2bf(fmaxf(a4[3], 0.f));
            *(ushort4*)&hTF[(((nt * 2 + sK) * 16 + lr) * 4 + qK) * 8 + j0] = hv;
        }
    }
    __syncthreads();

    // P3: ker-GEMM M=128(pad),K=64,N=32. Wave w -> m-tiles {2w,2w+1}; skip mt=7 (pad).
#pragma unroll
    for (int mi = 0; mi < 2; ++mi) {
        int mt = w * 2 + mi;
        if (mt == 7) break;
        short8 aw[2];
#pragma unroll
        for (int s = 0; s < 2; ++s)
            aw[s] = *(const short8*)&wsb[(mt * 16 + lr) * 64 + s * 32 + quad * 8];
#pragma unroll
        for (int nt = 0; nt < 2; ++nt) {
            floatx4 a4 = {0.f, 0.f, 0.f, 0.f};
#pragma unroll
            for (int s = 0; s < 2; ++s) {
                short8 bf = *(const short8*)&hTF[(((nt * 2 + s) * 16 + lr) * 4 + quad) * 8];
                a4 = __builtin_amdgcn_mfma_f32_16x16x32_bf16(aw[s], bf, a4, 0, 0, 0);
            }
            int r0 = mt * 16 + quad * 4;
            int n  = nt * 16 + lr;
#pragma unroll
            for (int r = 0; r < 4; ++r)
                ks[(r0 + r) * KS_STR + n] = f2bf(a4[r]);
        }
    }
    __syncthreads();

    // P4: involution — windows from frag LDS + register halo
    int g = c >> 4;
    float aslope = pa[0], gam = gamma[c], bet = beta[c];
    float xwin[38];
    xwin[0] = haloL[0]; xwin[1] = haloL[1]; xwin[2] = haloL[2];
#pragma unroll
    for (int j = 0; j < 32; ++j) xwin[3 + j] = bf2f(xsF[fragaddr(j, c)]);
    xwin[35] = haloR[0]; xwin[36] = haloR[1]; xwin[37] = haloR[2];

    float acc[32];
#pragma unroll
    for (int j = 0; j < 32; ++j) acc[j] = 0.f;
#pragma unroll
    for (int k = 0; k < 7; ++k) {
        const ushort_t* krow = &ks[(g * 7 + k) * KS_STR];
#pragma unroll
        for (int ch = 0; ch < 4; ++ch) {
            ushort4 kp0 = *(const ushort4*)&krow[ch * 8];
            ushort4 kp1 = *(const ushort4*)&krow[ch * 8 + 4];
            float kv0 = bf2f(kp0.x), kv1 = bf2f(kp0.y), kv2 = bf2f(kp0.z), kv3 = bf2f(kp0.w);
            float kv4 = bf2f(kp1.x), kv5 = bf2f(kp1.y), kv6 = bf2f(kp1.z), kv7 = bf2f(kp1.w);
            acc[ch*8+0] = fmaf(kv0, xwin[ch*8 + 0 + k], acc[ch*8+0]);
            acc[ch*8+1] = fmaf(kv1, xwin[ch*8 + 1 + k], acc[ch*8+1]);
            acc[ch*8+2] = fmaf(kv2, xwin[ch*8 + 2 + k], acc[ch*8+2]);
            acc[ch*8+3] = fmaf(kv3, xwin[ch*8 + 3 + k], acc[ch*8+3]);
            acc[ch*8+4] = fmaf(kv4, xwin[ch*8 + 4 + k], acc[ch*8+4]);
            acc[ch*8+5] = fmaf(kv5, xwin[ch*8 + 5 + k], acc[ch*8+5]);
            acc[ch*8+6] = fmaf(kv6, xwin[ch*8 + 6 + k], acc[ch*8+6]);
            acc[ch*8+7] = fmaf(kv7, xwin[ch*8 + 7 + k], acc[ch*8+7]);
        }
    }
    __syncthreads();   // all xsF window reads complete before overwrite

    // PReLU + pre-norm bf16 in-place (stats read it back)
#pragma unroll
    for (int j = 0; j < 32; ++j) {
        acc[j] = acc[j] >= 0.f ? acc[j] : aslope * acc[j];
        xsF[fragaddr(j, c)] = f2bf(acc[j]);
    }
    __syncthreads();

    // LN stats (reduction buffers overlay hTF — dead after P3)
    float* red1   = (float*)hTF;
    float* red2   = red1 + 256;
    float* mean_s = red2 + 256;
    float* rstd_s = mean_s + 32;
    {
        int lloc = t >> 3, seg = t & 7;
        float s1 = 0.f, s2 = 0.f;
#pragma unroll
        for (int q = 0; q < 4; ++q) {
            ushort4 v0 = *(const ushort4*)&xsF[fragaddr(lloc, seg * 32 + q * 8)];
            ushort4 v1 = *(const ushort4*)&xsF[fragaddr(lloc, seg * 32 + q * 8 + 4)];
            float f0 = bf2f(v0.x), f1 = bf2f(v0.y), f2v = bf2f(v0.z), f3 = bf2f(v0.w);
            float f4 = bf2f(v1.x), f5 = bf2f(v1.y), f6 = bf2f(v1.z), f7 = bf2f(v1.w);
            s1 += ((f0 + f1) + (f2v + f3)) + ((f4 + f5) + (f6 + f7));
            s2 += f0*f0 + f1*f1 + f2v*f2v + f3*f3 + f4*f4 + f5*f5 + f6*f6 + f7*f7;
        }
        red1[t] = s1; red2[t] = s2;
    }
    __syncthreads();
    if (t < 32) {
        float s1 = 0.f, s2 = 0.f;
#pragma unroll
        for (int i = 0; i < 8; ++i) { s1 += red1[t * 8 + i]; s2 += red2[t * 8 + i]; }
        float mu  = s1 * (1.f / 256.f);
        float var = s2 * (1.f / 256.f) - mu * mu;
        mean_s[t] = mu;
        rstd_s[t] = rsqrtf(var + 1e-5f);
    }
    __syncthreads();
#pragma unroll
    for (int j = 0; j < 32; ++j) {
        float v = (acc[j] - mean_s[j]) * rstd_s[j] * gam + bet;
        xsF[fragaddr(j, c)] = f2bf(v);
    }
    __syncthreads();

    // P5: [main;skip](512x256) @ xn(256x32); wave w -> rows [w*128,(w+1)*128)
#pragma unroll
    for (int mi = 0; mi < 8; ++mi) {
        int mt = w * 8 + mi;
        const ushort_t* arow = wb + (size_t)(mt * 16 + lr) * 256 + quad * 8;
        short8 a[8];
#pragma unroll
        for (int s = 0; s < 8; ++s) a[s] = *(const short8*)(arow + s * 32);
#pragma unroll
        for (int nt = 0; nt < 2; ++nt) {
            floatx4 a4 = {0.f, 0.f, 0.f, 0.f};
#pragma unroll
            for (int s = 0; s < 8; ++s) {
                short8 bfr = *(const short8*)&xsF[(((nt * 8 + s) * 16 + lr) * 4 + quad) * 8];
                a4 = __builtin_amdgcn_mfma_f32_16x16x32_bf16(a[s], bfr, a4, 0, 0, 0);
            }
            int m = mt * 16 + quad * 4;
            int l = l0 + nt * 16 + lr;
            if (mt < 16) {
                size_t base = ((size_t)b * C_DIM + m) * L_DIM + l;
#pragma unroll
                for (int r = 0; r < 4; ++r)
                    out[base + (size_t)r * L_DIM] = a4[r] + x[base + (size_t)r * L_DIM];
            } else {
                size_t base = SKIP_OFF + ((size_t)b * C_DIM + (m - 256)) * L_DIM + l;
#pragma unroll
                for (int r = 0; r < 4; ++r)
                    out[base + (size_t)r * L_DIM] = a4[r];
            }
        }
    }
}

extern "C" void kernel_launch(void* const* d_in, const int* in_sizes, int n_in,
                              void* d_out, int out_size, void* d_ws, size_t ws_size,
                              hipStream_t stream) {
    const float* x     = (const float*)d_in[0];
    const float* w_red = (const float*)d_in[1];
    const float* w_spn = (const float*)d_in[2];
    const float* pa    = (const float*)d_in[3];
    const float* gam   = (const float*)d_in[4];
    const float* bet   = (const float*)d_in[5];
    const float* w_m   = (const float*)d_in[6];
    const float* w_s   = (const float*)d_in[7];
    float* out = (float*)d_out;

    char* ws = (char*)d_ws;
    ushort_t* wb  = (ushort_t*)(ws);                       // 262144 B
    ushort_t* wrb = (ushort_t*)(ws + 262144);              // 32768 B
    ushort_t* wsb = (ushort_t*)(ws + 294912);              // 16384 B

    k0_prep<<<608, 256, 0, stream>>>(w_m, w_s, w_red, w_spn, wb, wrb, wsb);
    k_fused<<<2048, 256, 0, stream>>>(x, wrb, wsb, wb, pa, gam, bet, out);
}

// Round 2
// 262.931 us; speedup vs baseline: 1.0613x; 1.0613x over previous
//
#include <hip/hip_runtime.h>
#include <stdint.h>

#define C_DIM 256
#define L_DIM 8192
#define B_DIM 8
#define SKIP_OFF ((size_t)B_DIM * C_DIM * L_DIM)

using short8  = __attribute__((ext_vector_type(8))) short;
using floatx4 = __attribute__((ext_vector_type(4))) float;
typedef unsigned short ushort_t;

__device__ __forceinline__ ushort_t f2bf(float f) {
    union { float f; uint32_t u; } v; v.f = f;
    uint32_t u = v.u;
    return (ushort_t)((u + 0x7fff + ((u >> 16) & 1)) >> 16);
}
__device__ __forceinline__ float bf2f(ushort_t h) {
    union { uint32_t u; float f; } v; v.u = ((uint32_t)h) << 16;
    return v.f;
}

// frag-linear 32x256 bf16 tile: element (l, c) at
// [l>>4][c>>5][l&15][(c>>3)&3][c&7]  -> B-frag reads are lane-linear ds_read_b128
__device__ __forceinline__ int fragaddr(int l, int c) {
    return ((((l >> 4) * 8 + (c >> 5)) * 16 + (l & 15)) * 4 + ((c >> 3) & 3)) * 8 + (c & 7);
}

// ---------------------------------------------------------------------------
// K0: weight prep.
// wbF bf16: frag-linear [w_main;w_skip] (512x256): element (m,k) at
//   ((mt*8 + s)*16 + lr)*32 + quad*8 + j   (mt=m>>4, lr=m&15, s=k>>5,
//   quad=(k>>3)&3, j=k&7)  -> per-wave A-frag loads are 1KB-contiguous.
// wrb bf16[64][256] row-major; wsb bf16[128][64] (w_span padded 112->128).
// ---------------------------------------------------------------------------
__global__ __launch_bounds__(256) void k0_prep(const float* __restrict__ wm,
                                               const float* __restrict__ wk,
                                               const float* __restrict__ wr,
                                               const float* __restrict__ wsp,
                                               ushort_t* __restrict__ wbF,
                                               ushort_t* __restrict__ wrb,
                                               ushort_t* __restrict__ wsb) {
    int i = blockIdx.x * 256 + threadIdx.x;
    if (i < 131072) {
        int m = i >> 8, k = i & 255;
        float v = (m < 256) ? wm[m * 256 + k] : wk[(m - 256) * 256 + k];
        int mt = m >> 4, lr = m & 15, s = k >> 5, q = (k >> 3) & 3, j = k & 7;
        wbF[(((mt * 8 + s) * 16 + lr) * 32) + q * 8 + j] = f2bf(v);
    } else if (i < 147456) {
        wrb[i - 131072] = f2bf(wr[i - 131072]);
    } else if (i < 155648) {
        int j = i - 147456;
        int r = j >> 6, cc = j & 63;
        wsb[j] = (r < 112) ? f2bf(wsp[r * 64 + cc]) : (ushort_t)0;
    }
}

// ---------------------------------------------------------------------------
// K_FRONT: per (b, 32-l tile): x -> frag LDS; h = relu(Wr@x) MFMA;
// ker = Wsp@h MFMA -> LDS; involution from LDS windows (+reg halo);
// PReLU -> LayerNorm -> export xn tile (frag-linear, 16KB) to global.
// ---------------------------------------------------------------------------
#define KS_STR 40
__global__ __launch_bounds__(256) void k_front(const float* __restrict__ x,
                                               const ushort_t* __restrict__ wrb,
                                               const ushort_t* __restrict__ wsb,
                                               const float* __restrict__ pa,
                                               const float* __restrict__ gamma,
                                               const float* __restrict__ beta,
                                               ushort_t* __restrict__ xnG) {
    __shared__ __align__(16) ushort_t xsF[8192];        // 16384 B frag x tile; later xn
    __shared__ __align__(16) ushort_t hTF[2048];        // 4096 B h frag; later LN reductions
    __shared__ __align__(16) ushort_t ks[112 * KS_STR]; // 8960 B ker tile

    int t = threadIdx.x;
    int b = blockIdx.x >> 8;
    int l0 = (blockIdx.x & 255) * 32;
    const float* xb = x + (size_t)b * C_DIM * L_DIM;

    // halo: 3 left + 3 right per channel, fp32 registers (issued first, long-latency)
    int c = t;
    float haloL[3], haloR[3];
#pragma unroll
    for (int j = 0; j < 3; ++j) {
        int ll = l0 - 3 + j;
        haloL[j] = (ll >= 0) ? xb[(size_t)c * L_DIM + ll] : 0.f;
        int rr = l0 + 32 + j;
        haloR[j] = (rr < L_DIM) ? xb[(size_t)c * L_DIM + rr] : 0.f;
    }

    // P1: load x tile (coalesced float4 along l), cvt, scatter to frag LDS
    {
        int lo = (t & 7) * 4;
        int cb = t >> 3;
#pragma unroll
        for (int j = 0; j < 8; ++j) {
            int cc = cb + j * 32;
            float4 v = *(const float4*)&xb[(size_t)cc * L_DIM + l0 + lo];
            xsF[fragaddr(lo + 0, cc)] = f2bf(v.x);
            xsF[fragaddr(lo + 1, cc)] = f2bf(v.y);
            xsF[fragaddr(lo + 2, cc)] = f2bf(v.z);
            xsF[fragaddr(lo + 3, cc)] = f2bf(v.w);
        }
    }
    __syncthreads();

    int w = t >> 6, lane = t & 63, lr = lane & 15, quad = lane >> 4;

    // P2: h-GEMM M=64,K=256,N=32. Wave w -> rows w*16..+15. ReLU -> hTF frag.
    {
        short8 af[8];
#pragma unroll
        for (int s = 0; s < 8; ++s)
            af[s] = *(const short8*)&wrb[(w * 16 + lr) * 256 + s * 32 + quad * 8];
#pragma unroll
        for (int nt = 0; nt < 2; ++nt) {
            floatx4 a4 = {0.f, 0.f, 0.f, 0.f};
#pragma unroll
            for (int s = 0; s < 8; ++s) {
                short8 bf = *(const short8*)&xsF[(((nt * 8 + s) * 16 + lr) * 4 + quad) * 8];
                a4 = __builtin_amdgcn_mfma_f32_16x16x32_bf16(af[s], bf, a4, 0, 0, 0);
            }
            // C/D: n = nt*16+lr, r = w*16 + quad*4 + reg
            int r0 = w * 16 + quad * 4;
            int sK = r0 >> 5, qK = (r0 >> 3) & 3, j0 = r0 & 7;
            ushort4 hv;
            hv.x = f2bf(fmaxf(a4[0], 0.f));
            hv.y = f2bf(fmaxf(a4[1], 0.f));
            hv.z = f2bf(fmaxf(a4[2], 0.f));
            hv.w = f2bf(fmaxf(a4[3], 0.f));
            *(ushort4*)&hTF[(((nt * 2 + sK) * 16 + lr) * 4 + qK) * 8 + j0] = hv;
        }
    }
    __syncthreads();

    // P3: ker-GEMM M=128(pad),K=64,N=32. Wave w -> m-tiles {2w,2w+1}; skip mt=7 (pad).
#pragma unroll
    for (int mi = 0; mi < 2; ++mi) {
        int mt = w * 2 + mi;
        if (mt == 7) break;
        short8 aw[2];
#pragma unroll
        for (int s = 0; s < 2; ++s)
            aw[s] = *(const short8*)&wsb[(mt * 16 + lr) * 64 + s * 32 + quad * 8];
#pragma unroll
        for (int nt = 0; nt < 2; ++nt) {
            floatx4 a4 = {0.f, 0.f, 0.f, 0.f};
#pragma unroll
            for (int s = 0; s < 2; ++s) {
                short8 bf = *(const short8*)&hTF[(((nt * 2 + s) * 16 + lr) * 4 + quad) * 8];
                a4 = __builtin_amdgcn_mfma_f32_16x16x32_bf16(aw[s], bf, a4, 0, 0, 0);
            }
            int r0 = mt * 16 + quad * 4;
            int n  = nt * 16 + lr;
#pragma unroll
            for (int r = 0; r < 4; ++r)
                ks[(r0 + r) * KS_STR + n] = f2bf(a4[r]);
        }
    }
    __syncthreads();

    // P4: involution — windows from frag LDS + register halo
    int g = c >> 4;
    float aslope = pa[0], gam = gamma[c], bet = beta[c];
    float xwin[38];
    xwin[0] = haloL[0]; xwin[1] = haloL[1]; xwin[2] = haloL[2];
#pragma unroll
    for (int j = 0; j < 32; ++j) xwin[3 + j] = bf2f(xsF[fragaddr(j, c)]);
    xwin[35] = haloR[0]; xwin[36] = haloR[1]; xwin[37] = haloR[2];

    float acc[32];
#pragma unroll
    for (int j = 0; j < 32; ++j) acc[j] = 0.f;
#pragma unroll
    for (int k = 0; k < 7; ++k) {
        const ushort_t* krow = &ks[(g * 7 + k) * KS_STR];
#pragma unroll
        for (int ch = 0; ch < 4; ++ch) {
            ushort4 kp0 = *(const ushort4*)&krow[ch * 8];
            ushort4 kp1 = *(const ushort4*)&krow[ch * 8 + 4];
            float kv0 = bf2f(kp0.x), kv1 = bf2f(kp0.y), kv2 = bf2f(kp0.z), kv3 = bf2f(kp0.w);
            float kv4 = bf2f(kp1.x), kv5 = bf2f(kp1.y), kv6 = bf2f(kp1.z), kv7 = bf2f(kp1.w);
            acc[ch*8+0] = fmaf(kv0, xwin[ch*8 + 0 + k], acc[ch*8+0]);
            acc[ch*8+1] = fmaf(kv1, xwin[ch*8 + 1 + k], acc[ch*8+1]);
            acc[ch*8+2] = fmaf(kv2, xwin[ch*8 + 2 + k], acc[ch*8+2]);
            acc[ch*8+3] = fmaf(kv3, xwin[ch*8 + 3 + k], acc[ch*8+3]);
            acc[ch*8+4] = fmaf(kv4, xwin[ch*8 + 4 + k], acc[ch*8+4]);
            acc[ch*8+5] = fmaf(kv5, xwin[ch*8 + 5 + k], acc[ch*8+5]);
            acc[ch*8+6] = fmaf(kv6, xwin[ch*8 + 6 + k], acc[ch*8+6]);
            acc[ch*8+7] = fmaf(kv7, xwin[ch*8 + 7 + k], acc[ch*8+7]);
        }
    }
    __syncthreads();   // all xsF window reads complete before overwrite

    // PReLU + pre-norm bf16 in-place (stats read it back)
#pragma unroll
    for (int j = 0; j < 32; ++j) {
        acc[j] = acc[j] >= 0.f ? acc[j] : aslope * acc[j];
        xsF[fragaddr(j, c)] = f2bf(acc[j]);
    }
    __syncthreads();

    // LN stats (reduction buffers overlay hTF — dead after P3)
    float* red1   = (float*)hTF;
    float* red2   = red1 + 256;
    float* mean_s = red2 + 256;
    float* rstd_s = mean_s + 32;
    {
        int lloc = t >> 3, seg = t & 7;
        float s1 = 0.f, s2 = 0.f;
#pragma unroll
        for (int q = 0; q < 4; ++q) {
            ushort4 v0 = *(const ushort4*)&xsF[fragaddr(lloc, seg * 32 + q * 8)];
            ushort4 v1 = *(const ushort4*)&xsF[fragaddr(lloc, seg * 32 + q * 8 + 4)];
            float f0 = bf2f(v0.x), f1 = bf2f(v0.y), f2v = bf2f(v0.z), f3 = bf2f(v0.w);
            float f4 = bf2f(v1.x), f5 = bf2f(v1.y), f6 = bf2f(v1.z), f7 = bf2f(v1.w);
            s1 += ((f0 + f1) + (f2v + f3)) + ((f4 + f5) + (f6 + f7));
            s2 += f0*f0 + f1*f1 + f2v*f2v + f3*f3 + f4*f4 + f5*f5 + f6*f6 + f7*f7;
        }
        red1[t] = s1; red2[t] = s2;
    }
    __syncthreads();
    if (t < 32) {
        float s1 = 0.f, s2 = 0.f;
#pragma unroll
        for (int i = 0; i < 8; ++i) { s1 += red1[t * 8 + i]; s2 += red2[t * 8 + i]; }
        float mu  = s1 * (1.f / 256.f);
        float var = s2 * (1.f / 256.f) - mu * mu;
        mean_s[t] = mu;
        rstd_s[t] = rsqrtf(var + 1e-5f);
    }
    __syncthreads();
#pragma unroll
    for (int j = 0; j < 32; ++j) {
        float v = (acc[j] - mean_s[j]) * rstd_s[j] * gam + bet;
        xsF[fragaddr(j, c)] = f2bf(v);
    }
    __syncthreads();

    // export xn tile (16KB, frag-linear) — coalesced uint4 copy
    {
        const uint4* src = (const uint4*)xsF;
        uint4* dst = (uint4*)(xnG + (size_t)blockIdx.x * 8192);
#pragma unroll
        for (int j = 0; j < 4; ++j) dst[t + j * 256] = src[t + j * 256];
    }
}

// ---------------------------------------------------------------------------
// K_GEMM: pure epilogue GEMM. out[512x256] = [w_main;w_skip] @ xn, +x residual
// on the main half. Per block: (b, 64-l tile) -> N=64, M=512, K=256.
// B panel (two 16KB frag tiles) staged in LDS; B-frag ds_read_b128 lane-linear
// conflict-free; A-frags 1KB-contiguous global loads from L2-resident wbF.
// ---------------------------------------------------------------------------
__global__ __launch_bounds__(256) void k_gemm(const ushort_t* __restrict__ xnG,
                                              const ushort_t* __restrict__ wbF,
                                              const float* __restrict__ x,
                                              float* __restrict__ out) {
    __shared__ __align__(16) ushort_t xnLds[16384];   // 32 KB: two frag tiles

    int t = threadIdx.x;
    int b  = blockIdx.x >> 7;
    int lt = blockIdx.x & 127;
    int l0 = lt * 64;

    // stage B panel (32 KB contiguous)
    {
        const uint4* src = (const uint4*)(xnG + (size_t)(b * 256 + lt * 2) * 8192);
        uint4* dst = (uint4*)xnLds;
#pragma unroll
        for (int j = 0; j < 8; ++j) dst[t + j * 256] = src[t + j * 256];
    }
    __syncthreads();

    int w = t >> 6, lane = t & 63, lr = lane & 15, quad = lane >> 4;

#pragma unroll
    for (int grp = 0; grp < 2; ++grp) {
        int mtbase = w * 8 + grp * 4;
        floatx4 acc[4][4];
#pragma unroll
        for (int mi = 0; mi < 4; ++mi)
#pragma unroll
            for (int nt = 0; nt < 4; ++nt)
                acc[mi][nt] = (floatx4){0.f, 0.f, 0.f, 0.f};

#pragma unroll
        for (int s = 0; s < 8; ++s) {
            short8 Bf[4];
#pragma unroll
            for (int nt = 0; nt < 4; ++nt)
                Bf[nt] = *(const short8*)&xnLds[(nt >> 1) * 8192 +
                         ((((nt & 1) * 8 + s) * 16 + lr) * 4 + quad) * 8];
            short8 Af[4];
#pragma unroll
            for (int mi = 0; mi < 4; ++mi)
                Af[mi] = *(const short8*)&wbF[(size_t)(((mtbase + mi) * 8 + s) * 16 + lr) * 32 + quad * 8];
#pragma unroll
            for (int mi = 0; mi < 4; ++mi)
#pragma unroll
                for (int nt = 0; nt < 4; ++nt)
                    acc[mi][nt] = __builtin_amdgcn_mfma_f32_16x16x32_bf16(Af[mi], Bf[nt], acc[mi][nt], 0, 0, 0);
        }

        if (mtbase < 16) {
            // main half: + residual
#pragma unroll
            for (int mi = 0; mi < 4; ++mi) {
                int m = (mtbase + mi) * 16 + quad * 4;
#pragma unroll
                for (int nt = 0; nt < 4; ++nt) {
                    int l = l0 + nt * 16 + lr;
                    size_t base = ((size_t)b * C_DIM + m) * L_DIM + l;
#pragma unroll
                    for (int r = 0; r < 4; ++r)
                        out[base + (size_t)r * L_DIM] = acc[mi][nt][r] + x[base + (size_t)r * L_DIM];
                }
            }
        } else {
#pragma unroll
            for (int mi = 0; mi < 4; ++mi) {
                int m = (mtbase + mi) * 16 + quad * 4 - 256;
#pragma unroll
                for (int nt = 0; nt < 4; ++nt) {
                    int l = l0 + nt * 16 + lr;
                    size_t base = SKIP_OFF + ((size_t)b * C_DIM + m) * L_DIM + l;
#pragma unroll
                    for (int r = 0; r < 4; ++r)
                        out[base + (size_t)r * L_DIM] = acc[mi][nt][r];
                }
            }
        }
    }
}

extern "C" void kernel_launch(void* const* d_in, const int* in_sizes, int n_in,
                              void* d_out, int out_size, void* d_ws, size_t ws_size,
                              hipStream_t stream) {
    const float* x     = (const float*)d_in[0];
    const float* w_red = (const float*)d_in[1];
    const float* w_spn = (const float*)d_in[2];
    const float* pa    = (const float*)d_in[3];
    const float* gam   = (const float*)d_in[4];
    const float* bet   = (const float*)d_in[5];
    const float* w_m   = (const float*)d_in[6];
    const float* w_s   = (const float*)d_in[7];
    float* out = (float*)d_out;

    char* ws = (char*)d_ws;
    ushort_t* wbF = (ushort_t*)(ws);                       // 262144 B
    ushort_t* wrb = (ushort_t*)(ws + 262144);              // 32768 B
    ushort_t* wsb = (ushort_t*)(ws + 294912);              // 16384 B
    ushort_t* xnG = (ushort_t*)(ws + 311296);              // 33554432 B

    k0_prep<<<608, 256, 0, stream>>>(w_m, w_s, w_red, w_spn, wbF, wrb, wsb);
    k_front<<<2048, 256, 0, stream>>>(x, wrb, wsb, pa, gam, bet, xnG);
    k_gemm<<<1024, 256, 0, stream>>>(xnG, wbF, x, out);
}

// Round 4
// 256.017 us; speedup vs baseline: 1.0900x; 1.0270x over previous
//
#include <hip/hip_runtime.h>
#include <stdint.h>

#define C_DIM 256
#define L_DIM 8192
#define B_DIM 8
#define SKIP_OFF ((size_t)B_DIM * C_DIM * L_DIM)

using short8  = __attribute__((ext_vector_type(8))) short;
using floatx4 = __attribute__((ext_vector_type(4))) float;
typedef unsigned short ushort_t;

__device__ __forceinline__ ushort_t f2bf(float f) {
    union { float f; uint32_t u; } v; v.f = f;
    uint32_t u = v.u;
    return (ushort_t)((u + 0x7fff + ((u >> 16) & 1)) >> 16);
}
__device__ __forceinline__ float bf2f(ushort_t h) {
    union { uint32_t u; float f; } v; v.u = ((uint32_t)h) << 16;
    return v.f;
}

// frag-linear 32x256 bf16 tile: element (l, c) at
// [l>>4][c>>5][l&15][(c>>3)&3][c&7]  -> B-frag reads are lane-linear ds_read_b128
__device__ __forceinline__ int fragaddr(int l, int c) {
    return ((((l >> 4) * 8 + (c >> 5)) * 16 + (l & 15)) * 4 + ((c >> 3) & 3)) * 8 + (c & 7);
}

// ---------------------------------------------------------------------------
// K0: weight prep.
// wbF bf16: frag-linear [w_main;w_skip] (512x256): element (m,k) at
//   ((mt*8 + s)*16 + lr)*32 + quad*8 + j  (A-frags: 1KB-contiguous per wave).
// wrb bf16[64][256] row-major; wsb bf16[128][64] (w_span padded 112->128).
// ---------------------------------------------------------------------------
__global__ __launch_bounds__(256) void k0_prep(const float* __restrict__ wm,
                                               const float* __restrict__ wk,
                                               const float* __restrict__ wr,
                                               const float* __restrict__ wsp,
                                               ushort_t* __restrict__ wbF,
                                               ushort_t* __restrict__ wrb,
                                               ushort_t* __restrict__ wsb) {
    int i = blockIdx.x * 256 + threadIdx.x;
    if (i < 131072) {
        int m = i >> 8, k = i & 255;
        float v = (m < 256) ? wm[m * 256 + k] : wk[(m - 256) * 256 + k];
        int mt = m >> 4, lr = m & 15, s = k >> 5, q = (k >> 3) & 3, j = k & 7;
        wbF[(((mt * 8 + s) * 16 + lr) * 32) + q * 8 + j] = f2bf(v);
    } else if (i < 147456) {
        wrb[i - 131072] = f2bf(wr[i - 131072]);
    } else if (i < 155648) {
        int j = i - 147456;
        int r = j >> 6, cc = j & 63;
        wsb[j] = (r < 112) ? f2bf(wsp[r * 64 + cc]) : (ushort_t)0;
    }
}

// ---------------------------------------------------------------------------
// K_FRONT: per (b, 32-l tile): x -> frag LDS; h = relu(Wr@x) MFMA;
// ker = Wsp@h MFMA -> LDS; involution from LDS windows (+float4 reg halo);
// PReLU -> LayerNorm (shfl partials, no red[] round-trip)
// -> export xn tile (frag-linear, 16KB) to global.
// ---------------------------------------------------------------------------
#define KS_STR 40
__global__ __launch_bounds__(256) void k_front(const float* __restrict__ x,
                                               const ushort_t* __restrict__ wrb,
                                               const ushort_t* __restrict__ wsb,
                                               const float* __restrict__ pa,
                                               const float* __restrict__ gamma,
                                               const float* __restrict__ beta,
                                               ushort_t* __restrict__ xnG) {
    __shared__ __align__(16) ushort_t xsF[8192];        // 16384 B frag x tile; later xn
    __shared__ __align__(16) ushort_t hTF[2048];        // 4096 B h frag; later LN stats
    __shared__ __align__(16) ushort_t ks[112 * KS_STR]; // 8960 B ker tile

    int t = threadIdx.x;
    int b = blockIdx.x >> 8;
    int l0 = (blockIdx.x & 255) * 32;
    const float* xb = x + (size_t)b * C_DIM * L_DIM;

    // halo: two guarded float4 loads per channel (issued first, long-latency)
    int c = t;
    float4 hL = {0.f, 0.f, 0.f, 0.f}, hR = {0.f, 0.f, 0.f, 0.f};
    if (l0 > 0)           hL = *(const float4*)&xb[(size_t)c * L_DIM + l0 - 4];
    if (l0 + 36 <= L_DIM) hR = *(const float4*)&xb[(size_t)c * L_DIM + l0 + 32];

    // P1: load x tile (coalesced float4 along l), cvt, scatter to frag LDS
    {
        int lo = (t & 7) * 4;
        int cb = t >> 3;
#pragma unroll
        for (int j = 0; j < 8; ++j) {
            int cc = cb + j * 32;
            float4 v = *(const float4*)&xb[(size_t)cc * L_DIM + l0 + lo];
            xsF[fragaddr(lo + 0, cc)] = f2bf(v.x);
            xsF[fragaddr(lo + 1, cc)] = f2bf(v.y);
            xsF[fragaddr(lo + 2, cc)] = f2bf(v.z);
            xsF[fragaddr(lo + 3, cc)] = f2bf(v.w);
        }
    }
    __syncthreads();

    int w = t >> 6, lane = t & 63, lr = lane & 15, quad = lane >> 4;

    // P2: h-GEMM M=64,K=256,N=32. Wave w -> rows w*16..+15. ReLU -> hTF frag.
    {
        short8 af[8];
#pragma unroll
        for (int s = 0; s < 8; ++s)
            af[s] = *(const short8*)&wrb[(w * 16 + lr) * 256 + s * 32 + quad * 8];
#pragma unroll
        for (int nt = 0; nt < 2; ++nt) {
            floatx4 a4 = {0.f, 0.f, 0.f, 0.f};
#pragma unroll
            for (int s = 0; s < 8; ++s) {
                short8 bf = *(const short8*)&xsF[(((nt * 8 + s) * 16 + lr) * 4 + quad) * 8];
                a4 = __builtin_amdgcn_mfma_f32_16x16x32_bf16(af[s], bf, a4, 0, 0, 0);
            }
            // C/D: n = nt*16+lr, r = w*16 + quad*4 + reg
            int r0 = w * 16 + quad * 4;
            int sK = r0 >> 5, qK = (r0 >> 3) & 3, j0 = r0 & 7;
            ushort4 hv;
            hv.x = f2bf(fmaxf(a4[0], 0.f));
            hv.y = f2bf(fmaxf(a4[1], 0.f));
            hv.z = f2bf(fmaxf(a4[2], 0.f));
            hv.w = f2bf(fmaxf(a4[3], 0.f));
            *(ushort4*)&hTF[(((nt * 2 + sK) * 16 + lr) * 4 + qK) * 8 + j0] = hv;
        }
    }
    __syncthreads();

    // P3: ker-GEMM M=128(pad),K=64,N=32. Wave w -> m-tiles {2w,2w+1}; skip mt=7.
#pragma unroll
    for (int mi = 0; mi < 2; ++mi) {
        int mt = w * 2 + mi;
        if (mt == 7) break;
        short8 aw[2];
#pragma unroll
        for (int s = 0; s < 2; ++s)
            aw[s] = *(const short8*)&wsb[(mt * 16 + lr) * 64 + s * 32 + quad * 8];
#pragma unroll
        for (int nt = 0; nt < 2; ++nt) {
            floatx4 a4 = {0.f, 0.f, 0.f, 0.f};
#pragma unroll
            for (int s = 0; s < 2; ++s) {
                short8 bf = *(const short8*)&hTF[(((nt * 2 + s) * 16 + lr) * 4 + quad) * 8];
                a4 = __builtin_amdgcn_mfma_f32_16x16x32_bf16(aw[s], bf, a4, 0, 0, 0);
            }
            int r0 = mt * 16 + quad * 4;
            int n  = nt * 16 + lr;
#pragma unroll
            for (int r = 0; r < 4; ++r)
                ks[(r0 + r) * KS_STR + n] = f2bf(a4[r]);
        }
    }
    __syncthreads();

    // P4: involution — windows from frag LDS + register halo
    int g = c >> 4;
    float aslope = pa[0], gam = gamma[c], bet = beta[c];
    float xwin[38];
    xwin[0] = hL.y; xwin[1] = hL.z; xwin[2] = hL.w;
#pragma unroll
    for (int j = 0; j < 32; ++j) xwin[3 + j] = bf2f(xsF[fragaddr(j, c)]);
    xwin[35] = hR.x; xwin[36] = hR.y; xwin[37] = hR.z;

    float acc[32];
#pragma unroll
    for (int j = 0; j < 32; ++j) acc[j] = 0.f;
#pragma unroll
    for (int k = 0; k < 7; ++k) {
        const ushort_t* krow = &ks[(g * 7 + k) * KS_STR];
#pragma unroll
        for (int ch = 0; ch < 4; ++ch) {
            ushort4 kp0 = *(const ushort4*)&krow[ch * 8];
            ushort4 kp1 = *(const ushort4*)&krow[ch * 8 + 4];
            float kv0 = bf2f(kp0.x), kv1 = bf2f(kp0.y), kv2 = bf2f(kp0.z), kv3 = bf2f(kp0.w);
            float kv4 = bf2f(kp1.x), kv5 = bf2f(kp1.y), kv6 = bf2f(kp1.z), kv7 = bf2f(kp1.w);
            acc[ch*8+0] = fmaf(kv0, xwin[ch*8 + 0 + k], acc[ch*8+0]);
            acc[ch*8+1] = fmaf(kv1, xwin[ch*8 + 1 + k], acc[ch*8+1]);
            acc[ch*8+2] = fmaf(kv2, xwin[ch*8 + 2 + k], acc[ch*8+2]);
            acc[ch*8+3] = fmaf(kv3, xwin[ch*8 + 3 + k], acc[ch*8+3]);
            acc[ch*8+4] = fmaf(kv4, xwin[ch*8 + 4 + k], acc[ch*8+4]);
            acc[ch*8+5] = fmaf(kv5, xwin[ch*8 + 5 + k], acc[ch*8+5]);
            acc[ch*8+6] = fmaf(kv6, xwin[ch*8 + 6 + k], acc[ch*8+6]);
            acc[ch*8+7] = fmaf(kv7, xwin[ch*8 + 7 + k], acc[ch*8+7]);
        }
    }
    __syncthreads();   // all xsF window reads complete before overwrite

    // PReLU + pre-norm bf16 in-place (stats read it back)
#pragma unroll
    for (int j = 0; j < 32; ++j) {
        acc[j] = acc[j] >= 0.f ? acc[j] : aslope * acc[j];
        xsF[fragaddr(j, c)] = f2bf(acc[j]);
    }
    __syncthreads();

    // LN stats: thread (lloc=t>>3, seg=t&7) sums its 32-c segment of row lloc,
    // then 3-step shfl_xor over the 8 in-wave seg-lanes (no LDS round-trip).
    float* mean_s = (float*)hTF;        // hTF dead after P3
    float* rstd_s = mean_s + 32;
    {
        int lloc = t >> 3, seg = t & 7;
        float s1 = 0.f, s2 = 0.f;
#pragma unroll
        for (int q = 0; q < 4; ++q) {
            ushort4 v0 = *(const ushort4*)&xsF[fragaddr(lloc, seg * 32 + q * 8)];
            ushort4 v1 = *(const ushort4*)&xsF[fragaddr(lloc, seg * 32 + q * 8 + 4)];
            float f0 = bf2f(v0.x), f1 = bf2f(v0.y), f2v = bf2f(v0.z), f3 = bf2f(v0.w);
            float f4 = bf2f(v1.x), f5 = bf2f(v1.y), f6 = bf2f(v1.z), f7 = bf2f(v1.w);
            s1 += ((f0 + f1) + (f2v + f3)) + ((f4 + f5) + (f6 + f7));
            s2 += f0*f0 + f1*f1 + f2v*f2v + f3*f3 + f4*f4 + f5*f5 + f6*f6 + f7*f7;
        }
        s1 += __shfl_xor(s1, 1); s2 += __shfl_xor(s2, 1);
        s1 += __shfl_xor(s1, 2); s2 += __shfl_xor(s2, 2);
        s1 += __shfl_xor(s1, 4); s2 += __shfl_xor(s2, 4);
        if (seg == 0) {
            float mu  = s1 * (1.f / 256.f);
            float var = s2 * (1.f / 256.f) - mu * mu;
            mean_s[lloc] = mu;
            rstd_s[lloc] = rsqrtf(var + 1e-5f);
        }
    }
    __syncthreads();
#pragma unroll
    for (int j = 0; j < 32; ++j) {
        float v = (acc[j] - mean_s[j]) * rstd_s[j] * gam + bet;
        xsF[fragaddr(j, c)] = f2bf(v);
    }
    __syncthreads();

    // export xn tile (16KB, frag-linear) — coalesced uint4 blit
    {
        const uint4* src = (const uint4*)xsF;
        uint4* dst = (uint4*)(xnG + (size_t)blockIdx.x * 8192);
#pragma unroll
        for (int j = 0; j < 4; ++j) dst[t + j * 256] = src[t + j * 256];
    }
}

// ---------------------------------------------------------------------------
// K_GEMM: pure epilogue GEMM. out[512x256] = [w_main;w_skip] @ xn, +x residual
// on the main half. Per block: (b, 64-l tile) -> N=64, M=512, K=256.
// B panel (two 16KB frag tiles) staged in LDS; B-frag ds_read_b128 lane-linear
// conflict-free; A-frags 1KB-contiguous global loads from L2-resident wbF.
// out is a pure 128MB stream -> nontemporal stores.
// ---------------------------------------------------------------------------
__global__ __launch_bounds__(256) void k_gemm(const ushort_t* __restrict__ xnG,
                                              const ushort_t* __restrict__ wbF,
                                              const float* __restrict__ x,
                                              float* __restrict__ out) {
    __shared__ __align__(16) ushort_t xnLds[16384];   // 32 KB: two frag tiles

    int t = threadIdx.x;
    int b  = blockIdx.x >> 7;
    int lt = blockIdx.x & 127;
    int l0 = lt * 64;

    // stage B panel (32 KB contiguous)
    {
        const uint4* src = (const uint4*)(xnG + (size_t)(b * 256 + lt * 2) * 8192);
        uint4* dst = (uint4*)xnLds;
#pragma unroll
        for (int j = 0; j < 8; ++j) dst[t + j * 256] = src[t + j * 256];
    }
    __syncthreads();

    int w = t >> 6, lane = t & 63, lr = lane & 15, quad = lane >> 4;

#pragma unroll
    for (int grp = 0; grp < 2; ++grp) {
        int mtbase = w * 8 + grp * 4;
        floatx4 acc[4][4];
#pragma unroll
        for (int mi = 0; mi < 4; ++mi)
#pragma unroll
            for (int nt = 0; nt < 4; ++nt)
                acc[mi][nt] = (floatx4){0.f, 0.f, 0.f, 0.f};

#pragma unroll
        for (int s = 0; s < 8; ++s) {
            short8 Bf[4];
#pragma unroll
            for (int nt = 0; nt < 4; ++nt)
                Bf[nt] = *(const short8*)&xnLds[(nt >> 1) * 8192 +
                         ((((nt & 1) * 8 + s) * 16 + lr) * 4 + quad) * 8];
            short8 Af[4];
#pragma unroll
            for (int mi = 0; mi < 4; ++mi)
                Af[mi] = *(const short8*)&wbF[(size_t)(((mtbase + mi) * 8 + s) * 16 + lr) * 32 + quad * 8];
#pragma unroll
            for (int mi = 0; mi < 4; ++mi)
#pragma unroll
                for (int nt = 0; nt < 4; ++nt)
                    acc[mi][nt] = __builtin_amdgcn_mfma_f32_16x16x32_bf16(Af[mi], Bf[nt], acc[mi][nt], 0, 0, 0);
        }

        if (mtbase < 16) {
            // main half: + residual
#pragma unroll
            for (int mi = 0; mi < 4; ++mi) {
                int m = (mtbase + mi) * 16 + quad * 4;
#pragma unroll
                for (int nt = 0; nt < 4; ++nt) {
                    int l = l0 + nt * 16 + lr;
                    size_t base = ((size_t)b * C_DIM + m) * L_DIM + l;
#pragma unroll
                    for (int r = 0; r < 4; ++r)
                        __builtin_nontemporal_store(acc[mi][nt][r] + x[base + (size_t)r * L_DIM],
                                                    &out[base + (size_t)r * L_DIM]);
                }
            }
        } else {
#pragma unroll
            for (int mi = 0; mi < 4; ++mi) {
                int m = (mtbase + mi) * 16 + quad * 4 - 256;
#pragma unroll
                for (int nt = 0; nt < 4; ++nt) {
                    int l = l0 + nt * 16 + lr;
                    size_t base = SKIP_OFF + ((size_t)b * C_DIM + m) * L_DIM + l;
#pragma unroll
                    for (int r = 0; r < 4; ++r)
                        __builtin_nontemporal_store(acc[mi][nt][r],
                                                    &out[base + (size_t)r * L_DIM]);
                }
            }
        }
    }
}

extern "C" void kernel_launch(void* const* d_in, const int* in_sizes, int n_in,
                              void* d_out, int out_size, void* d_ws, size_t ws_size,
                              hipStream_t stream) {
    const float* x     = (const float*)d_in[0];
    const float* w_red = (const float*)d_in[1];
    const float* w_spn = (const float*)d_in[2];
    const float* pa    = (const float*)d_in[3];
    const float* gam   = (const float*)d_in[4];
    const float* bet   = (const float*)d_in[5];
    const float* w_m   = (const float*)d_in[6];
    const float* w_s   = (const float*)d_in[7];
    float* out = (float*)d_out;

    char* ws = (char*)d_ws;
    ushort_t* wbF = (ushort_t*)(ws);                       // 262144 B
    ushort_t* wrb = (ushort_t*)(ws + 262144);              // 32768 B
    ushort_t* wsb = (ushort_t*)(ws + 294912);              // 16384 B
    ushort_t* xnG = (ushort_t*)(ws + 311296);              // 33554432 B

    k0_prep<<<608, 256, 0, stream>>>(w_m, w_s, w_red, w_spn, wbF, wrb, wsb);
    k_front<<<2048, 256, 0, stream>>>(x, wrb, wsb, pa, gam, bet, xnG);
    k_gemm<<<1024, 256, 0, stream>>>(xnG, wbF, x, out);
}

// Round 6
// 255.196 us; speedup vs baseline: 1.0935x; 1.0032x over previous
//
#include <hip/hip_runtime.h>
#include <stdint.h>

#define C_DIM 256
#define L_DIM 8192
#define B_DIM 8
#define SKIP_OFF ((size_t)B_DIM * C_DIM * L_DIM)

using short8  = __attribute__((ext_vector_type(8))) short;
using floatx4 = __attribute__((ext_vector_type(4))) float;
typedef unsigned short ushort_t;

__device__ __forceinline__ ushort_t f2bf(float f) {
    union { float f; uint32_t u; } v; v.f = f;
    uint32_t u = v.u;
    return (ushort_t)((u + 0x7fff + ((u >> 16) & 1)) >> 16);
}
__device__ __forceinline__ float bf2f(ushort_t h) {
    union { uint32_t u; float f; } v; v.u = ((uint32_t)h) << 16;
    return v.f;
}

// frag-linear 32x256 bf16 tile: element (l, c) at
// [l>>4][c>>5][l&15][(c>>3)&3][c&7]  -> B-frag reads are lane-linear ds_read_b128
__device__ __forceinline__ int fragaddr(int l, int c) {
    return ((((l >> 4) * 8 + (c >> 5)) * 16 + (l & 15)) * 4 + ((c >> 3) & 3)) * 8 + (c & 7);
}

// ---------------------------------------------------------------------------
// K0: weight prep.
// wbF bf16: frag-linear [w_main;w_skip] (512x256): element (m,k) at
//   ((mt*8 + s)*16 + lr)*32 + quad*8 + j  (A-frags: 1KB-contiguous per wave).
// wrb bf16[64][256] row-major; wsb bf16[128][64] (w_span padded 112->128).
// ---------------------------------------------------------------------------
__global__ __launch_bounds__(256) void k0_prep(const float* __restrict__ wm,
                                               const float* __restrict__ wk,
                                               const float* __restrict__ wr,
                                               const float* __restrict__ wsp,
                                               ushort_t* __restrict__ wbF,
                                               ushort_t* __restrict__ wrb,
                                               ushort_t* __restrict__ wsb) {
    int i = blockIdx.x * 256 + threadIdx.x;
    if (i < 131072) {
        int m = i >> 8, k = i & 255;
        float v = (m < 256) ? wm[m * 256 + k] : wk[(m - 256) * 256 + k];
        int mt = m >> 4, lr = m & 15, s = k >> 5, q = (k >> 3) & 3, j = k & 7;
        wbF[(((mt * 8 + s) * 16 + lr) * 32) + q * 8 + j] = f2bf(v);
    } else if (i < 147456) {
        wrb[i - 131072] = f2bf(wr[i - 131072]);
    } else if (i < 155648) {
        int j = i - 147456;
        int r = j >> 6, cc = j & 63;
        wsb[j] = (r < 112) ? f2bf(wsp[r * 64 + cc]) : (ushort_t)0;
    }
}

// ---------------------------------------------------------------------------
// K_FRONT: per (b, 32-l tile): x -> frag LDS; h = relu(Wr@x) MFMA;
// ker = Wsp@h MFMA -> LDS; involution from LDS windows (+float4 reg halo);
// PReLU -> LayerNorm (shfl partials, no red[] round-trip)
// -> export xn tile (frag-linear, 16KB) to global.   (unchanged from R4)
// ---------------------------------------------------------------------------
#define KS_STR 40
__global__ __launch_bounds__(256) void k_front(const float* __restrict__ x,
                                               const ushort_t* __restrict__ wrb,
                                               const ushort_t* __restrict__ wsb,
                                               const float* __restrict__ pa,
                                               const float* __restrict__ gamma,
                                               const float* __restrict__ beta,
                                               ushort_t* __restrict__ xnG) {
    __shared__ __align__(16) ushort_t xsF[8192];        // 16384 B frag x tile; later xn
    __shared__ __align__(16) ushort_t hTF[2048];        // 4096 B h frag; later LN stats
    __shared__ __align__(16) ushort_t ks[112 * KS_STR]; // 8960 B ker tile

    int t = threadIdx.x;
    int b = blockIdx.x >> 8;
    int l0 = (blockIdx.x & 255) * 32;
    const float* xb = x + (size_t)b * C_DIM * L_DIM;

    // halo: two guarded float4 loads per channel (issued first, long-latency)
    int c = t;
    float4 hL = {0.f, 0.f, 0.f, 0.f}, hR = {0.f, 0.f, 0.f, 0.f};
    if (l0 > 0)           hL = *(const float4*)&xb[(size_t)c * L_DIM + l0 - 4];
    if (l0 + 36 <= L_DIM) hR = *(const float4*)&xb[(size_t)c * L_DIM + l0 + 32];

    // P1: load x tile (coalesced float4 along l), cvt, scatter to frag LDS
    {
        int lo = (t & 7) * 4;
        int cb = t >> 3;
#pragma unroll
        for (int j = 0; j < 8; ++j) {
            int cc = cb + j * 32;
            float4 v = *(const float4*)&xb[(size_t)cc * L_DIM + l0 + lo];
            xsF[fragaddr(lo + 0, cc)] = f2bf(v.x);
            xsF[fragaddr(lo + 1, cc)] = f2bf(v.y);
            xsF[fragaddr(lo + 2, cc)] = f2bf(v.z);
            xsF[fragaddr(lo + 3, cc)] = f2bf(v.w);
        }
    }
    __syncthreads();

    int w = t >> 6, lane = t & 63, lr = lane & 15, quad = lane >> 4;

    // P2: h-GEMM M=64,K=256,N=32. Wave w -> rows w*16..+15. ReLU -> hTF frag.
    {
        short8 af[8];
#pragma unroll
        for (int s = 0; s < 8; ++s)
            af[s] = *(const short8*)&wrb[(w * 16 + lr) * 256 + s * 32 + quad * 8];
#pragma unroll
        for (int nt = 0; nt < 2; ++nt) {
            floatx4 a4 = {0.f, 0.f, 0.f, 0.f};
#pragma unroll
            for (int s = 0; s < 8; ++s) {
                short8 bf = *(const short8*)&xsF[(((nt * 8 + s) * 16 + lr) * 4 + quad) * 8];
                a4 = __builtin_amdgcn_mfma_f32_16x16x32_bf16(af[s], bf, a4, 0, 0, 0);
            }
            // C/D: n = nt*16+lr, r = w*16 + quad*4 + reg
            int r0 = w * 16 + quad * 4;
            int sK = r0 >> 5, qK = (r0 >> 3) & 3, j0 = r0 & 7;
            ushort4 hv;
            hv.x = f2bf(fmaxf(a4[0], 0.f));
            hv.y = f2bf(fmaxf(a4[1], 0.f));
            hv.z = f2bf(fmaxf(a4[2], 0.f));
            hv.w = f2bf(fmaxf(a4[3], 0.f));
            *(ushort4*)&hTF[(((nt * 2 + sK) * 16 + lr) * 4 + qK) * 8 + j0] = hv;
        }
    }
    __syncthreads();

    // P3: ker-GEMM M=128(pad),K=64,N=32. Wave w -> m-tiles {2w,2w+1}; skip mt=7.
#pragma unroll
    for (int mi = 0; mi < 2; ++mi) {
        int mt = w * 2 + mi;
        if (mt == 7) break;
        short8 aw[2];
#pragma unroll
        for (int s = 0; s < 2; ++s)
            aw[s] = *(const short8*)&wsb[(mt * 16 + lr) * 64 + s * 32 + quad * 8];
#pragma unroll
        for (int nt = 0; nt < 2; ++nt) {
            floatx4 a4 = {0.f, 0.f, 0.f, 0.f};
#pragma unroll
            for (int s = 0; s < 2; ++s) {
                short8 bf = *(const short8*)&hTF[(((nt * 2 + s) * 16 + lr) * 4 + quad) * 8];
                a4 = __builtin_amdgcn_mfma_f32_16x16x32_bf16(aw[s], bf, a4, 0, 0, 0);
            }
            int r0 = mt * 16 + quad * 4;
            int n  = nt * 16 + lr;
#pragma unroll
            for (int r = 0; r < 4; ++r)
                ks[(r0 + r) * KS_STR + n] = f2bf(a4[r]);
        }
    }
    __syncthreads();

    // P4: involution — windows from frag LDS + register halo
    int g = c >> 4;
    float aslope = pa[0], gam = gamma[c], bet = beta[c];
    float xwin[38];
    xwin[0] = hL.y; xwin[1] = hL.z; xwin[2] = hL.w;
#pragma unroll
    for (int j = 0; j < 32; ++j) xwin[3 + j] = bf2f(xsF[fragaddr(j, c)]);
    xwin[35] = hR.x; xwin[36] = hR.y; xwin[37] = hR.z;

    float acc[32];
#pragma unroll
    for (int j = 0; j < 32; ++j) acc[j] = 0.f;
#pragma unroll
    for (int k = 0; k < 7; ++k) {
        const ushort_t* krow = &ks[(g * 7 + k) * KS_STR];
#pragma unroll
        for (int ch = 0; ch < 4; ++ch) {
            ushort4 kp0 = *(const ushort4*)&krow[ch * 8];
            ushort4 kp1 = *(const ushort4*)&krow[ch * 8 + 4];
            float kv0 = bf2f(kp0.x), kv1 = bf2f(kp0.y), kv2 = bf2f(kp0.z), kv3 = bf2f(kp0.w);
            float kv4 = bf2f(kp1.x), kv5 = bf2f(kp1.y), kv6 = bf2f(kp1.z), kv7 = bf2f(kp1.w);
            acc[ch*8+0] = fmaf(kv0, xwin[ch*8 + 0 + k], acc[ch*8+0]);
            acc[ch*8+1] = fmaf(kv1, xwin[ch*8 + 1 + k], acc[ch*8+1]);
            acc[ch*8+2] = fmaf(kv2, xwin[ch*8 + 2 + k], acc[ch*8+2]);
            acc[ch*8+3] = fmaf(kv3, xwin[ch*8 + 3 + k], acc[ch*8+3]);
            acc[ch*8+4] = fmaf(kv4, xwin[ch*8 + 4 + k], acc[ch*8+4]);
            acc[ch*8+5] = fmaf(kv5, xwin[ch*8 + 5 + k], acc[ch*8+5]);
            acc[ch*8+6] = fmaf(kv6, xwin[ch*8 + 6 + k], acc[ch*8+6]);
            acc[ch*8+7] = fmaf(kv7, xwin[ch*8 + 7 + k], acc[ch*8+7]);
        }
    }
    __syncthreads();   // all xsF window reads complete before overwrite

    // PReLU + pre-norm bf16 in-place (stats read it back)
#pragma unroll
    for (int j = 0; j < 32; ++j) {
        acc[j] = acc[j] >= 0.f ? acc[j] : aslope * acc[j];
        xsF[fragaddr(j, c)] = f2bf(acc[j]);
    }
    __syncthreads();

    // LN stats: thread (lloc=t>>3, seg=t&7) sums its 32-c segment of row lloc,
    // then 3-step shfl_xor over the 8 in-wave seg-lanes (no LDS round-trip).
    float* mean_s = (float*)hTF;        // hTF dead after P3
    float* rstd_s = mean_s + 32;
    {
        int lloc = t >> 3, seg = t & 7;
        float s1 = 0.f, s2 = 0.f;
#pragma unroll
        for (int q = 0; q < 4; ++q) {
            ushort4 v0 = *(const ushort4*)&xsF[fragaddr(lloc, seg * 32 + q * 8)];
            ushort4 v1 = *(const ushort4*)&xsF[fragaddr(lloc, seg * 32 + q * 8 + 4)];
            float f0 = bf2f(v0.x), f1 = bf2f(v0.y), f2v = bf2f(v0.z), f3 = bf2f(v0.w);
            float f4 = bf2f(v1.x), f5 = bf2f(v1.y), f6 = bf2f(v1.z), f7 = bf2f(v1.w);
            s1 += ((f0 + f1) + (f2v + f3)) + ((f4 + f5) + (f6 + f7));
            s2 += f0*f0 + f1*f1 + f2v*f2v + f3*f3 + f4*f4 + f5*f5 + f6*f6 + f7*f7;
        }
        s1 += __shfl_xor(s1, 1); s2 += __shfl_xor(s2, 1);
        s1 += __shfl_xor(s1, 2); s2 += __shfl_xor(s2, 2);
        s1 += __shfl_xor(s1, 4); s2 += __shfl_xor(s2, 4);
        if (seg == 0) {
            float mu  = s1 * (1.f / 256.f);
            float var = s2 * (1.f / 256.f) - mu * mu;
            mean_s[lloc] = mu;
            rstd_s[lloc] = rsqrtf(var + 1e-5f);
        }
    }
    __syncthreads();
#pragma unroll
    for (int j = 0; j < 32; ++j) {
        float v = (acc[j] - mean_s[j]) * rstd_s[j] * gam + bet;
        xsF[fragaddr(j, c)] = f2bf(v);
    }
    __syncthreads();

    // export xn tile (16KB, frag-linear) — coalesced uint4 blit
    {
        const uint4* src = (const uint4*)xsF;
        uint4* dst = (uint4*)(xnG + (size_t)blockIdx.x * 8192);
#pragma unroll
        for (int j = 0; j < 4; ++j) dst[t + j * 256] = src[t + j * 256];
    }
}

// ---------------------------------------------------------------------------
// K_GEMM: pure epilogue GEMM. out[512x256] = [w_main;w_skip] @ xn, +x residual.
// SWAPPED-OPERAND MFMA: mfma(Bf, Af) puts, per thread, 4 CONSECUTIVE l at one
// m-row into acc (mapping: D[r] = out[m=mt*16+lr][l=l0+nt*16+quad*4+r])
// -> float4 residual loads + floatx4 nontemporal stores (full 64B segments;
// kills the 168-vs-128MB write amplification of the scalar-store epilogue).
// Loads and LDS layout identical to the verified R4 kernel.
// ---------------------------------------------------------------------------
__global__ __launch_bounds__(256) void k_gemm(const ushort_t* __restrict__ xnG,
                                              const ushort_t* __restrict__ wbF,
                                              const float* __restrict__ x,
                                              float* __restrict__ out) {
    __shared__ __align__(16) ushort_t xnLds[16384];   // 32 KB: two frag tiles

    int t = threadIdx.x;
    int b  = blockIdx.x >> 7;
    int lt = blockIdx.x & 127;
    int l0 = lt * 64;

    // stage B panel (32 KB contiguous)
    {
        const uint4* src = (const uint4*)(xnG + (size_t)(b * 256 + lt * 2) * 8192);
        uint4* dst = (uint4*)xnLds;
#pragma unroll
        for (int j = 0; j < 8; ++j) dst[t + j * 256] = src[t + j * 256];
    }
    __syncthreads();

    int w = t >> 6, lane = t & 63, lr = lane & 15, quad = lane >> 4;

#pragma unroll
    for (int grp = 0; grp < 2; ++grp) {
        int mtbase = w * 8 + grp * 4;
        floatx4 acc[4][4];
#pragma unroll
        for (int mi = 0; mi < 4; ++mi)
#pragma unroll
            for (int nt = 0; nt < 4; ++nt)
                acc[mi][nt] = (floatx4){0.f, 0.f, 0.f, 0.f};

#pragma unroll
        for (int s = 0; s < 8; ++s) {
            short8 Bf[4];
#pragma unroll
            for (int nt = 0; nt < 4; ++nt)
                Bf[nt] = *(const short8*)&xnLds[(nt >> 1) * 8192 +
                         ((((nt & 1) * 8 + s) * 16 + lr) * 4 + quad) * 8];
            short8 Af[4];
#pragma unroll
            for (int mi = 0; mi < 4; ++mi)
                Af[mi] = *(const short8*)&wbF[(size_t)(((mtbase + mi) * 8 + s) * 16 + lr) * 32 + quad * 8];
#pragma unroll
            for (int mi = 0; mi < 4; ++mi)
#pragma unroll
                for (int nt = 0; nt < 4; ++nt)
                    acc[mi][nt] = __builtin_amdgcn_mfma_f32_16x16x32_bf16(Bf[nt], Af[mi], acc[mi][nt], 0, 0, 0);
        }

        if (mtbase < 16) {
            // main half: + residual, float4 load + floatx4 NT store per (mi,nt)
#pragma unroll
            for (int mi = 0; mi < 4; ++mi) {
                int m = (mtbase + mi) * 16 + lr;
                size_t rowb = ((size_t)b * C_DIM + m) * L_DIM + l0 + quad * 4;
#pragma unroll
                for (int nt = 0; nt < 4; ++nt) {
                    size_t base = rowb + nt * 16;
                    float4 rx = *(const float4*)&x[base];
                    floatx4 o;
                    o[0] = acc[mi][nt][0] + rx.x;
                    o[1] = acc[mi][nt][1] + rx.y;
                    o[2] = acc[mi][nt][2] + rx.z;
                    o[3] = acc[mi][nt][3] + rx.w;
                    __builtin_nontemporal_store(o, (floatx4*)&out[base]);
                }
            }
        } else {
#pragma unroll
            for (int mi = 0; mi < 4; ++mi) {
                int m = (mtbase + mi) * 16 + lr - 256;
                size_t rowb = SKIP_OFF + ((size_t)b * C_DIM + m) * L_DIM + l0 + quad * 4;
#pragma unroll
                for (int nt = 0; nt < 4; ++nt) {
                    size_t base = rowb + nt * 16;
                    floatx4 o = acc[mi][nt];
                    __builtin_nontemporal_store(o, (floatx4*)&out[base]);
                }
            }
        }
    }
}

extern "C" void kernel_launch(void* const* d_in, const int* in_sizes, int n_in,
                              void* d_out, int out_size, void* d_ws, size_t ws_size,
                              hipStream_t stream) {
    const float* x     = (const float*)d_in[0];
    const float* w_red = (const float*)d_in[1];
    const float* w_spn = (const float*)d_in[2];
    const float* pa    = (const float*)d_in[3];
    const float* gam   = (const float*)d_in[4];
    const float* bet   = (const float*)d_in[5];
    const float* w_m   = (const float*)d_in[6];
    const float* w_s   = (const float*)d_in[7];
    float* out = (float*)d_out;

    char* ws = (char*)d_ws;
    ushort_t* wbF = (ushort_t*)(ws);                       // 262144 B
    ushort_t* wrb = (ushort_t*)(ws + 262144);              // 32768 B
    ushort_t* wsb = (ushort_t*)(ws + 294912);              // 16384 B
    ushort_t* xnG = (ushort_t*)(ws + 311296);              // 33554432 B

    k0_prep<<<608, 256, 0, stream>>>(w_m, w_s, w_red, w_spn, wbF, wrb, wsb);
    k_front<<<2048, 256, 0, stream>>>(x, wrb, wsb, pa, gam, bet, xnG);
    k_gemm<<<1024, 256, 0, stream>>>(xnG, wbF, x, out);
}